// Round 8
// baseline (643.430 us; speedup 1.0000x reference)
//
#include <hip/hip_runtime.h>

#define WAVE 64
#define LRELU(x) ((x) > 0.0f ? (x) : 0.2f * (x))

typedef __attribute__((ext_vector_type(8))) short bf16x8;
typedef __attribute__((ext_vector_type(4))) float f32x4;

__device__ __forceinline__ void gld16(const void* g, void* l) {
    __builtin_amdgcn_global_load_lds((const __attribute__((address_space(1))) unsigned int*)g,
                                     (__attribute__((address_space(3))) unsigned int*)l,
                                     16, 0, 0);
}

__device__ __forceinline__ unsigned short f2bf_hi(float f) {
    unsigned u = __builtin_bit_cast(unsigned, f);
    u += 0x7FFF + ((u >> 16) & 1);
    return (unsigned short)(u >> 16);
}

__device__ __forceinline__ float4 bf4_to_f32(ushort4 v) {
    float4 r;
    r.x = __builtin_bit_cast(float, (unsigned)v.x << 16);
    r.y = __builtin_bit_cast(float, (unsigned)v.y << 16);
    r.z = __builtin_bit_cast(float, (unsigned)v.z << 16);
    r.w = __builtin_bit_cast(float, (unsigned)v.w << 16);
    return r;
}

// truncation-hi split: hi = top16(f), lo = rne_bf16(f - hi)
__device__ __forceinline__ void split8(f32x4 a, f32x4 b, bf16x8& hi, bf16x8& lo) {
    float f[8] = {a[0], a[1], a[2], a[3], b[0], b[1], b[2], b[3]};
#pragma unroll
    for (int e = 0; e < 8; e++) {
        unsigned u = __builtin_bit_cast(unsigned, f[e]);
        float hf = __builtin_bit_cast(float, u & 0xFFFF0000u);
        float fl = f[e] - hf;
        unsigned u2 = __builtin_bit_cast(unsigned, fl);
        unsigned t2 = u2 + 0x7FFF + ((u2 >> 16) & 1);
        hi[e] = (short)(u >> 16);
        lo[e] = (short)(t2 >> 16);
    }
}

// ============ GEMM layer1, round-8 structure: B LDS double-buffered, A register
// ping-pong + single A LDS buffer. Both barriers are cheap drains (in-flight loads
// land under the ~930-cyc MFMA phase). 48 KB LDS -> 3 blocks/CU. K/32 must be even.
__global__ __launch_bounds__(256) void k_gemm_f32A(const float* __restrict__ A,
                                                   const unsigned short* __restrict__ Bh,
                                                   const unsigned short* __restrict__ Bl,
                                                   unsigned short* __restrict__ Cb,
                                                   float* __restrict__ asrc,
                                                   float* __restrict__ adst,
                                                   const float* __restrict__ att_s,
                                                   const float* __restrict__ att_d,
                                                   int M, int K) {
    __shared__ char smem[49152];
    char* SAH = smem;            // A hi: 32 frags x 256B = 8 KB
    char* SAL = smem + 8192;     // A lo: 8 KB
    char* SB0 = smem + 16384;    // B buf0: hi 8 KB + lo 8 KB
    char* SB1 = smem + 32768;    // B buf1

    const int tid = threadIdx.x, lane = tid & 63, w = tid >> 6;
    const int m16 = lane & 15, q = lane >> 4;
    const int row0 = blockIdx.x * 128, col0 = blockIdx.y * 128;

    f32x4 acc[4][4];
#pragma unroll
    for (int i = 0; i < 4; i++)
#pragma unroll
        for (int j = 0; j < 4; j++) acc[i][j] = (f32x4){0.f, 0.f, 0.f, 0.f};

    const int s_row = tid >> 1;
    const int s_mt  = s_row >> 4, s_m16 = s_row & 15;
    const int s_q0  = (tid & 1) * 2;
    int s_grow = row0 + s_row;
    if (s_grow > M - 1) s_grow = M - 1;
    const f32x4* aptr = (const f32x4*)&A[(size_t)s_grow * K] + (tid & 1) * 4;
    const int s_off = (s_mt * 4 + s_q0) * 256 + s_m16 * 16;

    const int b_rloc = lane >> 2;
    const int b_kb   = (lane & 3) * 16;

    f32x4 r0[4], r1[4];

    auto stageB = [&](int k0, char* SB) {
#pragma unroll
        for (int s = 0; s < 2; s++) {
            int c = w * 2 + s;
            int brow = col0 + c * 16 + b_rloc;
            gld16((const char*)Bh + ((size_t)brow * K + k0) * 2 + b_kb, SB + c * 1024);
            gld16((const char*)Bl + ((size_t)brow * K + k0) * 2 + b_kb, SB + 8192 + c * 1024);
        }
    };
    auto loadA = [&](f32x4* r) {
        r[0] = aptr[0]; r[1] = aptr[1]; r[2] = aptr[2]; r[3] = aptr[3];
        aptr += 8;
    };
    auto splitA = [&](f32x4* r) {
        bf16x8 h0, l0, h1, l1;
        split8(r[0], r[1], h0, l0);
        split8(r[2], r[3], h1, l1);
        *(bf16x8*)(SAH + s_off)       = h0;
        *(bf16x8*)(SAL + s_off)       = l0;
        *(bf16x8*)(SAH + s_off + 256) = h1;
        *(bf16x8*)(SAL + s_off + 256) = l1;
    };
    auto mfma = [&](char* SB) {
        bf16x8 bh[4], bl[4];
#pragma unroll
        for (int nt = 0; nt < 4; nt++) {
            int r = (w & 1) * 64 + nt * 16 + m16;
            bh[nt] = *(bf16x8*)(SB + r * 64 + q * 16);
            bl[nt] = *(bf16x8*)(SB + 8192 + r * 64 + q * 16);
        }
#pragma unroll
        for (int mt = 0; mt < 4; mt++) {
            int frag = ((w >> 1) * 4 + mt) * 4 + q;
            bf16x8 ah = *(bf16x8*)(SAH + frag * 256 + m16 * 16);
            bf16x8 al = *(bf16x8*)(SAL + frag * 256 + m16 * 16);
#pragma unroll
            for (int nt = 0; nt < 4; nt++) {
                acc[mt][nt] = __builtin_amdgcn_mfma_f32_16x16x32_bf16(ah, bh[nt], acc[mt][nt], 0, 0, 0);
                acc[mt][nt] = __builtin_amdgcn_mfma_f32_16x16x32_bf16(ah, bl[nt], acc[mt][nt], 0, 0, 0);
                acc[mt][nt] = __builtin_amdgcn_mfma_f32_16x16x32_bf16(al, bh[nt], acc[mt][nt], 0, 0, 0);
            }
        }
    };

    const int iters = K / 32;   // 24 for K=768 (even)
    // prologue: A(0)->r0, B(0)->SB0, split A(0), A(1)->r1
    loadA(r0);
    stageB(0, SB0);
    splitA(r0);
    loadA(r1);
    __syncthreads();   // publish A(0),B(0); one-time drain

    for (int i = 0; i < iters; i += 2) {
        // even sub-iter: compute on SB0 / A(i) in LDS; r1 = A(i+1)
        if (i + 1 < iters) stageB((i + 1) * 32, SB1);
        if (i + 2 < iters) loadA(r0);                 // r0 free
        mfma(SB0);
        __syncthreads();   // drains B(i+1)+A(i+2) (landed under MFMA)
        if (i + 1 < iters) {
            splitA(r1);    // A(i+1) -> LDS
            __syncthreads();   // cheap: only ds_writes outstanding
            // odd sub-iter: compute on SB1 / A(i+1); r0 = A(i+2)
            if (i + 2 < iters) stageB((i + 2) * 32, SB0);
            if (i + 3 < iters) loadA(r1);
            mfma(SB1);
            __syncthreads();
            if (i + 2 < iters) {
                splitA(r0);
                __syncthreads();
            }
        }
    }

    const int rbase = row0 + (w >> 1) * 64;
    const int cbase = col0 + (w & 1) * 64;
#pragma unroll
    for (int mt = 0; mt < 4; mt++)
#pragma unroll
        for (int r = 0; r < 4; r++) {
            int row = rbase + mt * 16 + q * 4 + r;
            if (row < M) {
#pragma unroll
                for (int nt = 0; nt < 4; nt++)
                    Cb[(size_t)row * 256 + cbase + nt * 16 + m16] = f2bf_hi(acc[mt][nt][r]);
            }
        }
    float as_v[4], ad_v[4];
#pragma unroll
    for (int nt = 0; nt < 4; nt++) {
        as_v[nt] = att_s[cbase + nt * 16 + m16];
        ad_v[nt] = att_d[cbase + nt * 16 + m16];
    }
#pragma unroll
    for (int mt = 0; mt < 4; mt++)
#pragma unroll
        for (int r = 0; r < 4; r++) {
            float s = 0.f, d = 0.f;
#pragma unroll
            for (int nt = 0; nt < 4; nt++) {
                float v = acc[mt][nt][r];
                s = fmaf(v, as_v[nt], s);
                d = fmaf(v, ad_v[nt], d);
            }
#pragma unroll
            for (int off = 1; off < 16; off <<= 1) {
                s += __shfl_xor(s, off);
                d += __shfl_xor(d, off);
            }
            int row = rbase + mt * 16 + q * 4 + r;
            if (m16 == 0 && row < M) {
                atomicAdd(&asrc[row], s);
                atomicAdd(&adst[row], d);
            }
        }
}

// ============ GEMM layer2: A pre-split bf16 planes [Mpad][K]; round-7 structure.
__global__ __launch_bounds__(256) void k_gemm_bf16A(const unsigned short* __restrict__ Ah,
                                                    const unsigned short* __restrict__ Al,
                                                    const unsigned short* __restrict__ Bh,
                                                    const unsigned short* __restrict__ Bl,
                                                    unsigned short* __restrict__ Cb,
                                                    float* __restrict__ asrc,
                                                    float* __restrict__ adst,
                                                    const float* __restrict__ att_s,
                                                    const float* __restrict__ att_d,
                                                    int M, int K) {
    __shared__ char smem[32768];
    char* SAH = smem;
    char* SAL = smem + 8192;
    char* SBH = smem + 16384;
    char* SBL = smem + 24576;

    const int tid = threadIdx.x, lane = tid & 63, w = tid >> 6;
    const int m16 = lane & 15, q = lane >> 4;
    const int row0 = blockIdx.x * 128, col0 = blockIdx.y * 128;

    f32x4 acc[4][4];
#pragma unroll
    for (int i = 0; i < 4; i++)
#pragma unroll
        for (int j = 0; j < 4; j++) acc[i][j] = (f32x4){0.f, 0.f, 0.f, 0.f};

    const int rloc = lane >> 2;
    const int kb   = (lane & 3) * 16;

    for (int k0 = 0; k0 < K; k0 += 32) {
#pragma unroll
        for (int s = 0; s < 2; s++) {
            int c = w * 2 + s;
            int arow = row0 + c * 16 + rloc;
            int brow = col0 + c * 16 + rloc;
            gld16((const char*)Ah + ((size_t)arow * K + k0) * 2 + kb, SAH + c * 1024);
            gld16((const char*)Al + ((size_t)arow * K + k0) * 2 + kb, SAL + c * 1024);
            gld16((const char*)Bh + ((size_t)brow * K + k0) * 2 + kb, SBH + c * 1024);
            gld16((const char*)Bl + ((size_t)brow * K + k0) * 2 + kb, SBL + c * 1024);
        }
        __syncthreads();

        bf16x8 bh[4], bl[4];
#pragma unroll
        for (int nt = 0; nt < 4; nt++) {
            int r = (w & 1) * 64 + nt * 16 + m16;
            bh[nt] = *(bf16x8*)(SBH + r * 64 + q * 16);
            bl[nt] = *(bf16x8*)(SBL + r * 64 + q * 16);
        }
#pragma unroll
        for (int mt = 0; mt < 4; mt++) {
            int r = (w >> 1) * 64 + mt * 16 + m16;
            bf16x8 ah = *(bf16x8*)(SAH + r * 64 + q * 16);
            bf16x8 al = *(bf16x8*)(SAL + r * 64 + q * 16);
#pragma unroll
            for (int nt = 0; nt < 4; nt++) {
                acc[mt][nt] = __builtin_amdgcn_mfma_f32_16x16x32_bf16(ah, bh[nt], acc[mt][nt], 0, 0, 0);
                acc[mt][nt] = __builtin_amdgcn_mfma_f32_16x16x32_bf16(ah, bl[nt], acc[mt][nt], 0, 0, 0);
                acc[mt][nt] = __builtin_amdgcn_mfma_f32_16x16x32_bf16(al, bh[nt], acc[mt][nt], 0, 0, 0);
            }
        }
        __syncthreads();
    }

    const int rbase = row0 + (w >> 1) * 64;
    const int cbase = col0 + (w & 1) * 64;
#pragma unroll
    for (int mt = 0; mt < 4; mt++)
#pragma unroll
        for (int r = 0; r < 4; r++) {
            int row = rbase + mt * 16 + q * 4 + r;
            if (row < M) {
#pragma unroll
                for (int nt = 0; nt < 4; nt++)
                    Cb[(size_t)row * 256 + cbase + nt * 16 + m16] = f2bf_hi(acc[mt][nt][r]);
            }
        }
    float as_v[4], ad_v[4];
#pragma unroll
    for (int nt = 0; nt < 4; nt++) {
        as_v[nt] = att_s[cbase + nt * 16 + m16];
        ad_v[nt] = att_d[cbase + nt * 16 + m16];
    }
#pragma unroll
    for (int mt = 0; mt < 4; mt++)
#pragma unroll
        for (int r = 0; r < 4; r++) {
            float s = 0.f, d = 0.f;
#pragma unroll
            for (int nt = 0; nt < 4; nt++) {
                float v = acc[mt][nt][r];
                s = fmaf(v, as_v[nt], s);
                d = fmaf(v, ad_v[nt], d);
            }
#pragma unroll
            for (int off = 1; off < 16; off <<= 1) {
                s += __shfl_xor(s, off);
                d += __shfl_xor(d, off);
            }
            int row = rbase + mt * 16 + q * 4 + r;
            if (m16 == 0 && row < M) {
                atomicAdd(&asrc[row], s);
                atomicAdd(&adst[row], d);
            }
        }
}

// ---------------- W [K][256] fp32 -> BThi/BTlo [256][K] bf16
__global__ __launch_bounds__(256) void k_convB(const float* __restrict__ W,
                                               unsigned short* __restrict__ BThi,
                                               unsigned short* __restrict__ BTlo, int K) {
    int idx = blockIdx.x * 256 + threadIdx.x;
    int k = idx >> 8, n = idx & 255;
    if (k >= K) return;
    float f = W[(size_t)k * 256 + n];
    unsigned u = __builtin_bit_cast(unsigned, f);
    unsigned t = u + 0x7FFF + ((u >> 16) & 1);
    float hf = __builtin_bit_cast(float, t & 0xFFFF0000u);
    unsigned short lb = f2bf_hi(f - hf);
    BThi[(size_t)n * K + k] = (unsigned short)(t >> 16);
    BTlo[(size_t)n * K + k] = lb;
}

// ---------------- CSR build
__global__ __launch_bounds__(256) void k_degree(const int* __restrict__ dst,
                                                int* __restrict__ counts, int E) {
    int e = blockIdx.x * 256 + threadIdx.x;
    if (e < E) atomicAdd(&counts[dst[e]], 1);
}

__global__ __launch_bounds__(256) void k_part(const int* __restrict__ counts,
                                              int* __restrict__ psum, int N) {
    __shared__ int red[256];
    int tid = threadIdx.x;
    int i = blockIdx.x * 256 + tid;
    red[tid] = (i < N) ? counts[i] : 0;
    __syncthreads();
    for (int off = 128; off; off >>= 1) {
        if (tid < off) red[tid] += red[tid + off];
        __syncthreads();
    }
    if (tid == 0) psum[blockIdx.x] = red[0];
}

__global__ __launch_bounds__(256) void k_scan_part(int* __restrict__ psum, int nb,
                                                   int* __restrict__ total_out) {
    __shared__ int s[256];
    int tid = threadIdx.x;
    int v = (tid < nb) ? psum[tid] : 0;
    s[tid] = v;
    __syncthreads();
    for (int off = 1; off < 256; off <<= 1) {
        int t = (tid >= off) ? s[tid - off] : 0;
        __syncthreads();
        s[tid] += t;
        __syncthreads();
    }
    if (tid < nb) psum[tid] = s[tid] - v;
    if (tid == 255) *total_out = s[255];
}

__global__ __launch_bounds__(256) void k_rowptr(const int* __restrict__ counts,
                                                const int* __restrict__ psum,
                                                int* __restrict__ rowptr,
                                                int* __restrict__ cursor, int N) {
    __shared__ int s[256];
    int tid = threadIdx.x;
    int i = blockIdx.x * 256 + tid;
    int v = (i < N) ? counts[i] : 0;
    s[tid] = v;
    __syncthreads();
    for (int off = 1; off < 256; off <<= 1) {
        int t = (tid >= off) ? s[tid - off] : 0;
        __syncthreads();
        s[tid] += t;
        __syncthreads();
    }
    if (i < N) {
        int excl = psum[blockIdx.x] + s[tid] - v;
        rowptr[i] = excl;
        cursor[i] = excl;
    }
}

__global__ __launch_bounds__(256) void k_scatter(const int* __restrict__ src,
                                                 const int* __restrict__ dst,
                                                 int* __restrict__ cursor,
                                                 int* __restrict__ col, int E) {
    int e = blockIdx.x * 256 + threadIdx.x;
    if (e < E) {
        int p = atomicAdd(&cursor[dst[e]], 1);
        col[p] = src[e];
    }
}

// ---------------- single-pass softmax+gather: m = LRELU(gmax+ad) upper bound
// (LRELU monotone, asrc<=gmax => valid softmax shift; e-m >= ~-10, no underflow).
__global__ __launch_bounds__(256) void k_edge(const unsigned short* __restrict__ hb,
                                              const float* __restrict__ asrc,
                                              const float* __restrict__ adst,
                                              const float* __restrict__ gmaxv,
                                              const int* __restrict__ rowptr,
                                              const int* __restrict__ col,
                                              const float* __restrict__ bias,
                                              float* __restrict__ outf,
                                              unsigned short* __restrict__ outh,
                                              unsigned short* __restrict__ outl,
                                              const float* __restrict__ gw,
                                              const float* __restrict__ gb,
                                              float* __restrict__ gatep, int N) {
    int wid = threadIdx.x >> 6;
    int lane = threadIdx.x & 63;
    int node = blockIdx.x * 4 + wid;
    if (node >= N) return;
    int j = rowptr[node], end = rowptr[node + 1];
    float ad = adst[node];
    float gm = gmaxv[0] + ad;
    float m = LRELU(gm);

    float wself = __expf(LRELU(asrc[node] + ad) - m);
    float denom = wself;
    float4 hv = bf4_to_f32(*(const ushort4*)&hb[(size_t)node * 256 + lane * 4]);
    float ax = wself * hv.x, ay = wself * hv.y, az = wself * hv.z, aw = wself * hv.w;

    for (; j + 8 <= end; j += 8) {
        int s0 = col[j], s1 = col[j+1], s2 = col[j+2], s3 = col[j+3];
        int s4 = col[j+4], s5 = col[j+5], s6 = col[j+6], s7 = col[j+7];
        float w0 = __expf(LRELU(asrc[s0] + ad) - m);
        float w1 = __expf(LRELU(asrc[s1] + ad) - m);
        float w2 = __expf(LRELU(asrc[s2] + ad) - m);
        float w3 = __expf(LRELU(asrc[s3] + ad) - m);
        float w4 = __expf(LRELU(asrc[s4] + ad) - m);
        float w5 = __expf(LRELU(asrc[s5] + ad) - m);
        float w6 = __expf(LRELU(asrc[s6] + ad) - m);
        float w7 = __expf(LRELU(asrc[s7] + ad) - m);
        denom += w0 + w1 + w2 + w3 + w4 + w5 + w6 + w7;
        float4 h0 = bf4_to_f32(*(const ushort4*)&hb[(size_t)s0 * 256 + lane * 4]);
        float4 h1 = bf4_to_f32(*(const ushort4*)&hb[(size_t)s1 * 256 + lane * 4]);
        float4 h2 = bf4_to_f32(*(const ushort4*)&hb[(size_t)s2 * 256 + lane * 4]);
        float4 h3 = bf4_to_f32(*(const ushort4*)&hb[(size_t)s3 * 256 + lane * 4]);
        float4 h4 = bf4_to_f32(*(const ushort4*)&hb[(size_t)s4 * 256 + lane * 4]);
        float4 h5 = bf4_to_f32(*(const ushort4*)&hb[(size_t)s5 * 256 + lane * 4]);
        float4 h6 = bf4_to_f32(*(const ushort4*)&hb[(size_t)s6 * 256 + lane * 4]);
        float4 h7 = bf4_to_f32(*(const ushort4*)&hb[(size_t)s7 * 256 + lane * 4]);
        ax = fmaf(w0,h0.x, fmaf(w1,h1.x, fmaf(w2,h2.x, fmaf(w3,h3.x,
             fmaf(w4,h4.x, fmaf(w5,h5.x, fmaf(w6,h6.x, fmaf(w7,h7.x, ax))))))));
        ay = fmaf(w0,h0.y, fmaf(w1,h1.y, fmaf(w2,h2.y, fmaf(w3,h3.y,
             fmaf(w4,h4.y, fmaf(w5,h5.y, fmaf(w6,h6.y, fmaf(w7,h7.y, ay))))))));
        az = fmaf(w0,h0.z, fmaf(w1,h1.z, fmaf(w2,h2.z, fmaf(w3,h3.z,
             fmaf(w4,h4.z, fmaf(w5,h5.z, fmaf(w6,h6.z, fmaf(w7,h7.z, az))))))));
        aw = fmaf(w0,h0.w, fmaf(w1,h1.w, fmaf(w2,h2.w, fmaf(w3,h3.w,
             fmaf(w4,h4.w, fmaf(w5,h5.w, fmaf(w6,h6.w, fmaf(w7,h7.w, aw))))))));
    }
    for (; j < end; j++) {
        int s = col[j];
        float wgt = __expf(LRELU(asrc[s] + ad) - m);
        denom += wgt;
        float4 hx = bf4_to_f32(*(const ushort4*)&hb[(size_t)s * 256 + lane * 4]);
        ax = fmaf(wgt, hx.x, ax); ay = fmaf(wgt, hx.y, ay);
        az = fmaf(wgt, hx.z, az); aw = fmaf(wgt, hx.w, aw);
    }
    float inv = 1.0f / (denom + 1e-16f);
    float4 bv = *(const float4*)&bias[lane * 4];
    float ox = fmaxf(fmaf(ax, inv, bv.x), 0.0f);
    float oy = fmaxf(fmaf(ay, inv, bv.y), 0.0f);
    float oz = fmaxf(fmaf(az, inv, bv.z), 0.0f);
    float ow = fmaxf(fmaf(aw, inv, bv.w), 0.0f);
    if (outf) {
        float4 o = make_float4(ox, oy, oz, ow);
        *(float4*)&outf[(size_t)node * 256 + lane * 4] = o;
    }
    if (outh) {
        float of[4] = {ox, oy, oz, ow};
        unsigned long long ph = 0, pl = 0;
#pragma unroll
        for (int e = 0; e < 4; e++) {
            unsigned u = __builtin_bit_cast(unsigned, of[e]);
            unsigned t = u + 0x7FFF + ((u >> 16) & 1);
            float hf = __builtin_bit_cast(float, t & 0xFFFF0000u);
            float fl = of[e] - hf;
            unsigned u2 = __builtin_bit_cast(unsigned, fl);
            unsigned t2 = u2 + 0x7FFF + ((u2 >> 16) & 1);
            ph |= ((unsigned long long)(t >> 16)) << (16 * e);
            pl |= ((unsigned long long)(t2 >> 16)) << (16 * e);
        }
        *(unsigned long long*)&outh[(size_t)node * 256 + lane * 4] = ph;
        *(unsigned long long*)&outl[(size_t)node * 256 + lane * 4] = pl;
    }
    if (gatep) {
        float4 gv = *(const float4*)&gw[lane * 4];
        float s = ox * gv.x + oy * gv.y + oz * gv.z + ow * gv.w;
#pragma unroll
        for (int off = 32; off; off >>= 1) s += __shfl_xor(s, off);
        if (lane == 0) gatep[node] = s + gb[0];
    }
}

// ---------------- reductions
__global__ __launch_bounds__(256) void k_pmax(const float* __restrict__ v, int N,
                                              float* __restrict__ pmax) {
    __shared__ float red[256];
    int tid = threadIdx.x;
    float m = -3.0e38f;
    for (int i = blockIdx.x * 256 + tid; i < N; i += gridDim.x * 256) m = fmaxf(m, v[i]);
    red[tid] = m;
    __syncthreads();
    for (int off = 128; off; off >>= 1) {
        if (tid < off) red[tid] = fmaxf(red[tid], red[tid + off]);
        __syncthreads();
    }
    if (tid == 0) pmax[blockIdx.x] = red[0];
}

__global__ __launch_bounds__(64) void k_fold(const float* __restrict__ p,
                                             float* __restrict__ o) {
    int lane = threadIdx.x;
    float m = p[lane];
#pragma unroll
    for (int off = 32; off; off >>= 1) m = fmaxf(m, __shfl_xor(m, off));
    if (lane == 0) o[0] = m;
}

__global__ __launch_bounds__(256) void k_gmid(const float* __restrict__ pmax, int nb,
                                              float* __restrict__ scal,
                                              float* __restrict__ gout) {
    __shared__ float red[256];
    int tid = threadIdx.x;
    red[tid] = (tid < nb) ? pmax[tid] : -3.0e38f;
    __syncthreads();
    for (int off = 128; off; off >>= 1) {
        if (tid < off) red[tid] = fmaxf(red[tid], red[tid + off]);
        __syncthreads();
    }
    if (tid == 0) { scal[0] = red[0]; scal[1] = 0.0f; }
    gout[tid] = 0.0f;
}

__global__ __launch_bounds__(256) void k_gout(const float* __restrict__ h,
                                              const float* __restrict__ gate,
                                              float* __restrict__ scal_rw,
                                              float* __restrict__ gout, int N) {
    int f = threadIdx.x;
    float gmax = scal_rw[0];
    float acc = 0.0f, sumw = 0.0f;
    for (int i = blockIdx.x; i < N; i += gridDim.x) {
        float w = __expf(gate[i] - gmax);
        acc = fmaf(w, h[(size_t)i * 256 + f], acc);
        sumw += w;
    }
    atomicAdd(&gout[f], acc);
    if (f == 0) atomicAdd(&scal_rw[1], sumw);
}

__global__ __launch_bounds__(256) void k_final(const float* __restrict__ gout,
                                               const float* __restrict__ scal,
                                               float* __restrict__ out) {
    int f = threadIdx.x;
    out[f] = gout[f] / scal[1];
}

extern "C" void kernel_launch(void* const* d_in, const int* in_sizes, int n_in,
                              void* d_out, int out_size, void* d_ws, size_t ws_size,
                              hipStream_t stream) {
    const float* x   = (const float*)d_in[0];
    const int*   ei  = (const int*)d_in[1];
    const float* W1  = (const float*)d_in[2];
    const float* b1  = (const float*)d_in[3];
    const float* as1 = (const float*)d_in[4];
    const float* ad1 = (const float*)d_in[5];
    const float* W2  = (const float*)d_in[6];
    const float* b2  = (const float*)d_in[7];
    const float* as2 = (const float*)d_in[8];
    const float* ad2 = (const float*)d_in[9];
    const float* gw  = (const float*)d_in[10];
    const float* gb  = (const float*)d_in[11];
    float* out = (float*)d_out;

    const int N = in_sizes[0] / 768;   // 50000
    const int E = in_sizes[1] / 2;     // 800000
    const int Mpad = (N + 127) & ~127; // 50048
    const int* srcA = ei;
    const int* dstA = ei + E;

    char* w = (char*)d_ws;
    auto alloc = [&](size_t bytes) -> void* {
        void* p = (void*)w;
        w += (bytes + 255) & ~(size_t)255;
        return p;
    };
    unsigned short* bufHb = (unsigned short*)alloc((size_t)N * 256 * 2);
    unsigned short* X2h = (unsigned short*)alloc((size_t)Mpad * 256 * 2);
    unsigned short* X2l = (unsigned short*)alloc((size_t)Mpad * 256 * 2);
    float* bufX = (float*)X2h;  // alias: X2 planes dead after GEMM2
    float* asrc   = (float*)alloc((size_t)N * 4);
    float* adst   = (float*)alloc((size_t)N * 4);
    float* gate   = (float*)alloc((size_t)N * 4);
    int*   counts = (int*)alloc((size_t)N * 4);
    int*   rowptr = (int*)alloc((size_t)(N + 1) * 4);
    int*   cursor = (int*)alloc((size_t)N * 4);
    int*   colbuf = (int*)alloc((size_t)E * 4);
    int*   psum   = (int*)alloc(256 * 4);
    float* pmax   = (float*)alloc(256 * 4);
    float* gmaxv  = (float*)alloc(4 * 4);
    float* scal   = (float*)alloc(8 * 4);
    float* gout   = (float*)alloc(256 * 4);
    unsigned short* BT1h = (unsigned short*)alloc((size_t)256 * 768 * 2);
    unsigned short* BT1l = (unsigned short*)alloc((size_t)256 * 768 * 2);
    unsigned short* BT2h = (unsigned short*)alloc((size_t)256 * 256 * 2);
    unsigned short* BT2l = (unsigned short*)alloc((size_t)256 * 256 * 2);

    const int eb  = (E + 255) / 256;
    const int nb4 = (N + 3) / 4;
    const int nb  = (N + 255) / 256;
    const dim3 gg(Mpad / 128, 2);

    // weight split/transpose
    k_convB<<<768, 256, 0, stream>>>(W1, BT1h, BT1l, 768);
    k_convB<<<256, 256, 0, stream>>>(W2, BT2h, BT2l, 256);

    // CSR by dst
    (void)hipMemsetAsync(counts, 0, (size_t)N * 4, stream);
    k_degree<<<eb, 256, 0, stream>>>(dstA, counts, E);
    k_part<<<nb, 256, 0, stream>>>(counts, psum, N);
    k_scan_part<<<1, 256, 0, stream>>>(psum, nb, rowptr + N);
    k_rowptr<<<nb, 256, 0, stream>>>(counts, psum, rowptr, cursor, N);
    k_scatter<<<eb, 256, 0, stream>>>(srcA, dstA, cursor, colbuf, E);

    // layer 1
    (void)hipMemsetAsync(asrc, 0, (size_t)N * 4, stream);
    (void)hipMemsetAsync(adst, 0, (size_t)N * 4, stream);
    k_gemm_f32A<<<gg, 256, 0, stream>>>(x, BT1h, BT1l, bufHb, asrc, adst, as1, ad1, N, 768);
    k_pmax<<<64, 256, 0, stream>>>(asrc, N, pmax);
    k_fold<<<1, 64, 0, stream>>>(pmax, gmaxv);
    k_edge<<<nb4, 256, 0, stream>>>(bufHb, asrc, adst, gmaxv, rowptr, colbuf, b1,
                                    nullptr, X2h, X2l, nullptr, nullptr, nullptr, N);

    // layer 2
    (void)hipMemsetAsync(asrc, 0, (size_t)N * 4, stream);
    (void)hipMemsetAsync(adst, 0, (size_t)N * 4, stream);
    k_gemm_bf16A<<<gg, 256, 0, stream>>>(X2h, X2l, BT2h, BT2l, bufHb, asrc, adst, as2, ad2, N, 256);
    k_pmax<<<64, 256, 0, stream>>>(asrc, N, pmax);
    k_fold<<<1, 64, 0, stream>>>(pmax, gmaxv);
    k_edge<<<nb4, 256, 0, stream>>>(bufHb, asrc, adst, gmaxv, rowptr, colbuf, b2,
                                    bufX, nullptr, nullptr, gw, gb, gate, N);

    // global attention
    k_pmax<<<64, 256, 0, stream>>>(gate, N, pmax);
    k_gmid<<<1, 256, 0, stream>>>(pmax, 64, scal, gout);
    k_gout<<<256, 256, 0, stream>>>(bufX, gate, scal, gout, N);
    k_final<<<1, 256, 0, stream>>>(gout, scal, out);
}

// Round 9
// 634.973 us; speedup vs baseline: 1.0133x; 1.0133x over previous
//
#include <hip/hip_runtime.h>

#define WAVE 64
#define LRELU(x) ((x) > 0.0f ? (x) : 0.2f * (x))

typedef __attribute__((ext_vector_type(8))) short bf16x8;
typedef __attribute__((ext_vector_type(8))) unsigned short u16x8;
typedef __attribute__((ext_vector_type(4))) float f32x4;

__device__ __forceinline__ void gld16(const void* g, void* l) {
    __builtin_amdgcn_global_load_lds((const __attribute__((address_space(1))) unsigned int*)g,
                                     (__attribute__((address_space(3))) unsigned int*)l,
                                     16, 0, 0);
}

__device__ __forceinline__ unsigned short f2bf_hi(float f) {
    unsigned u = __builtin_bit_cast(unsigned, f);
    u += 0x7FFF + ((u >> 16) & 1);
    return (unsigned short)(u >> 16);
}

// truncation-hi split: hi = top16(f), lo = rne_bf16(f - hi)
__device__ __forceinline__ void split8(f32x4 a, f32x4 b, bf16x8& hi, bf16x8& lo) {
    float f[8] = {a[0], a[1], a[2], a[3], b[0], b[1], b[2], b[3]};
#pragma unroll
    for (int e = 0; e < 8; e++) {
        unsigned u = __builtin_bit_cast(unsigned, f[e]);
        float hf = __builtin_bit_cast(float, u & 0xFFFF0000u);
        float fl = f[e] - hf;
        unsigned u2 = __builtin_bit_cast(unsigned, fl);
        unsigned t2 = u2 + 0x7FFF + ((u2 >> 16) & 1);
        hi[e] = (short)(u >> 16);
        lo[e] = (short)(t2 >> 16);
    }
}

// ============ GEMM layer1 (round-7 structure — round-8 dbuf regressed: 48KB LDS cut
// occupancy 5->3 blocks/CU, the documented m132 failure). A register-prefetched fp32,
// split once at staging, fragment-major LDS. Fused epilogue: bf16 C + att dots.
__global__ __launch_bounds__(256) void k_gemm_f32A(const float* __restrict__ A,
                                                   const unsigned short* __restrict__ Bh,
                                                   const unsigned short* __restrict__ Bl,
                                                   unsigned short* __restrict__ Cb,
                                                   float* __restrict__ asrc,
                                                   float* __restrict__ adst,
                                                   const float* __restrict__ att_s,
                                                   const float* __restrict__ att_d,
                                                   int M, int K) {
    __shared__ char smem[32768];
    char* SAH = smem;            // A hi: 32 frags x 256B
    char* SAL = smem + 8192;     // A lo
    char* SBH = smem + 16384;    // B hi: 8 chunks x 1KB
    char* SBL = smem + 24576;    // B lo

    const int tid = threadIdx.x, lane = tid & 63, w = tid >> 6;
    const int m16 = lane & 15, q = lane >> 4;
    const int row0 = blockIdx.x * 128, col0 = blockIdx.y * 128;

    f32x4 acc[4][4];
#pragma unroll
    for (int i = 0; i < 4; i++)
#pragma unroll
        for (int j = 0; j < 4; j++) acc[i][j] = (f32x4){0.f, 0.f, 0.f, 0.f};

    const int s_row = tid >> 1;
    const int s_mt  = s_row >> 4, s_m16 = s_row & 15;
    const int s_q0  = (tid & 1) * 2;
    int s_grow = row0 + s_row;
    if (s_grow > M - 1) s_grow = M - 1;
    const f32x4* aptr = (const f32x4*)&A[(size_t)s_grow * K] + (tid & 1) * 4;
    const int s_off = (s_mt * 4 + s_q0) * 256 + s_m16 * 16;

    const int b_rloc = lane >> 2;
    const int b_kb   = (lane & 3) * 16;

    f32x4 pre0 = aptr[0], pre1 = aptr[1], pre2 = aptr[2], pre3 = aptr[3];

    for (int k0 = 0; k0 < K; k0 += 32) {
#pragma unroll
        for (int s = 0; s < 2; s++) {
            int c = w * 2 + s;
            int brow = col0 + c * 16 + b_rloc;
            gld16((const char*)Bh + ((size_t)brow * K + k0) * 2 + b_kb, SBH + c * 1024);
            gld16((const char*)Bl + ((size_t)brow * K + k0) * 2 + b_kb, SBL + c * 1024);
        }
        {
            bf16x8 h0, l0, h1, l1;
            split8(pre0, pre1, h0, l0);
            split8(pre2, pre3, h1, l1);
            *(bf16x8*)(SAH + s_off)       = h0;
            *(bf16x8*)(SAL + s_off)       = l0;
            *(bf16x8*)(SAH + s_off + 256) = h1;
            *(bf16x8*)(SAL + s_off + 256) = l1;
        }
        __syncthreads();

        if (k0 + 32 < K) {
            aptr += 8;
            pre0 = aptr[0]; pre1 = aptr[1]; pre2 = aptr[2]; pre3 = aptr[3];
        }

        bf16x8 bh[4], bl[4];
#pragma unroll
        for (int nt = 0; nt < 4; nt++) {
            int r = (w & 1) * 64 + nt * 16 + m16;
            bh[nt] = *(bf16x8*)(SBH + r * 64 + q * 16);
            bl[nt] = *(bf16x8*)(SBL + r * 64 + q * 16);
        }
#pragma unroll
        for (int mt = 0; mt < 4; mt++) {
            int frag = ((w >> 1) * 4 + mt) * 4 + q;
            bf16x8 ah = *(bf16x8*)(SAH + frag * 256 + m16 * 16);
            bf16x8 al = *(bf16x8*)(SAL + frag * 256 + m16 * 16);
#pragma unroll
            for (int nt = 0; nt < 4; nt++) {
                acc[mt][nt] = __builtin_amdgcn_mfma_f32_16x16x32_bf16(ah, bh[nt], acc[mt][nt], 0, 0, 0);
                acc[mt][nt] = __builtin_amdgcn_mfma_f32_16x16x32_bf16(ah, bl[nt], acc[mt][nt], 0, 0, 0);
                acc[mt][nt] = __builtin_amdgcn_mfma_f32_16x16x32_bf16(al, bh[nt], acc[mt][nt], 0, 0, 0);
            }
        }
        __syncthreads();
    }

    const int rbase = row0 + (w >> 1) * 64;
    const int cbase = col0 + (w & 1) * 64;
#pragma unroll
    for (int mt = 0; mt < 4; mt++)
#pragma unroll
        for (int r = 0; r < 4; r++) {
            int row = rbase + mt * 16 + q * 4 + r;
            if (row < M) {
#pragma unroll
                for (int nt = 0; nt < 4; nt++)
                    Cb[(size_t)row * 256 + cbase + nt * 16 + m16] = f2bf_hi(acc[mt][nt][r]);
            }
        }
    float as_v[4], ad_v[4];
#pragma unroll
    for (int nt = 0; nt < 4; nt++) {
        as_v[nt] = att_s[cbase + nt * 16 + m16];
        ad_v[nt] = att_d[cbase + nt * 16 + m16];
    }
#pragma unroll
    for (int mt = 0; mt < 4; mt++)
#pragma unroll
        for (int r = 0; r < 4; r++) {
            float s = 0.f, d = 0.f;
#pragma unroll
            for (int nt = 0; nt < 4; nt++) {
                float v = acc[mt][nt][r];
                s = fmaf(v, as_v[nt], s);
                d = fmaf(v, ad_v[nt], d);
            }
#pragma unroll
            for (int off = 1; off < 16; off <<= 1) {
                s += __shfl_xor(s, off);
                d += __shfl_xor(d, off);
            }
            int row = rbase + mt * 16 + q * 4 + r;
            if (m16 == 0 && row < M) {
                atomicAdd(&asrc[row], s);
                atomicAdd(&adst[row], d);
            }
        }
}

// ============ GEMM layer2: A pre-split bf16 planes [Mpad][K]; fused epilogue.
__global__ __launch_bounds__(256) void k_gemm_bf16A(const unsigned short* __restrict__ Ah,
                                                    const unsigned short* __restrict__ Al,
                                                    const unsigned short* __restrict__ Bh,
                                                    const unsigned short* __restrict__ Bl,
                                                    unsigned short* __restrict__ Cb,
                                                    float* __restrict__ asrc,
                                                    float* __restrict__ adst,
                                                    const float* __restrict__ att_s,
                                                    const float* __restrict__ att_d,
                                                    int M, int K) {
    __shared__ char smem[32768];
    char* SAH = smem;
    char* SAL = smem + 8192;
    char* SBH = smem + 16384;
    char* SBL = smem + 24576;

    const int tid = threadIdx.x, lane = tid & 63, w = tid >> 6;
    const int m16 = lane & 15, q = lane >> 4;
    const int row0 = blockIdx.x * 128, col0 = blockIdx.y * 128;

    f32x4 acc[4][4];
#pragma unroll
    for (int i = 0; i < 4; i++)
#pragma unroll
        for (int j = 0; j < 4; j++) acc[i][j] = (f32x4){0.f, 0.f, 0.f, 0.f};

    const int rloc = lane >> 2;
    const int kb   = (lane & 3) * 16;

    for (int k0 = 0; k0 < K; k0 += 32) {
#pragma unroll
        for (int s = 0; s < 2; s++) {
            int c = w * 2 + s;
            int arow = row0 + c * 16 + rloc;
            int brow = col0 + c * 16 + rloc;
            gld16((const char*)Ah + ((size_t)arow * K + k0) * 2 + kb, SAH + c * 1024);
            gld16((const char*)Al + ((size_t)arow * K + k0) * 2 + kb, SAL + c * 1024);
            gld16((const char*)Bh + ((size_t)brow * K + k0) * 2 + kb, SBH + c * 1024);
            gld16((const char*)Bl + ((size_t)brow * K + k0) * 2 + kb, SBL + c * 1024);
        }
        __syncthreads();

        bf16x8 bh[4], bl[4];
#pragma unroll
        for (int nt = 0; nt < 4; nt++) {
            int r = (w & 1) * 64 + nt * 16 + m16;
            bh[nt] = *(bf16x8*)(SBH + r * 64 + q * 16);
            bl[nt] = *(bf16x8*)(SBL + r * 64 + q * 16);
        }
#pragma unroll
        for (int mt = 0; mt < 4; mt++) {
            int r = (w >> 1) * 64 + mt * 16 + m16;
            bf16x8 ah = *(bf16x8*)(SAH + r * 64 + q * 16);
            bf16x8 al = *(bf16x8*)(SAL + r * 64 + q * 16);
#pragma unroll
            for (int nt = 0; nt < 4; nt++) {
                acc[mt][nt] = __builtin_amdgcn_mfma_f32_16x16x32_bf16(ah, bh[nt], acc[mt][nt], 0, 0, 0);
                acc[mt][nt] = __builtin_amdgcn_mfma_f32_16x16x32_bf16(ah, bl[nt], acc[mt][nt], 0, 0, 0);
                acc[mt][nt] = __builtin_amdgcn_mfma_f32_16x16x32_bf16(al, bh[nt], acc[mt][nt], 0, 0, 0);
            }
        }
        __syncthreads();
    }

    const int rbase = row0 + (w >> 1) * 64;
    const int cbase = col0 + (w & 1) * 64;
#pragma unroll
    for (int mt = 0; mt < 4; mt++)
#pragma unroll
        for (int r = 0; r < 4; r++) {
            int row = rbase + mt * 16 + q * 4 + r;
            if (row < M) {
#pragma unroll
                for (int nt = 0; nt < 4; nt++)
                    Cb[(size_t)row * 256 + cbase + nt * 16 + m16] = f2bf_hi(acc[mt][nt][r]);
            }
        }
    float as_v[4], ad_v[4];
#pragma unroll
    for (int nt = 0; nt < 4; nt++) {
        as_v[nt] = att_s[cbase + nt * 16 + m16];
        ad_v[nt] = att_d[cbase + nt * 16 + m16];
    }
#pragma unroll
    for (int mt = 0; mt < 4; mt++)
#pragma unroll
        for (int r = 0; r < 4; r++) {
            float s = 0.f, d = 0.f;
#pragma unroll
            for (int nt = 0; nt < 4; nt++) {
                float v = acc[mt][nt][r];
                s = fmaf(v, as_v[nt], s);
                d = fmaf(v, ad_v[nt], d);
            }
#pragma unroll
            for (int off = 1; off < 16; off <<= 1) {
                s += __shfl_xor(s, off);
                d += __shfl_xor(d, off);
            }
            int row = rbase + mt * 16 + q * 4 + r;
            if (m16 == 0 && row < M) {
                atomicAdd(&asrc[row], s);
                atomicAdd(&adst[row], d);
            }
        }
}

// ---------------- W [K][256] fp32 -> BThi/BTlo [256][K] bf16
__global__ __launch_bounds__(256) void k_convB(const float* __restrict__ W,
                                               unsigned short* __restrict__ BThi,
                                               unsigned short* __restrict__ BTlo, int K) {
    int idx = blockIdx.x * 256 + threadIdx.x;
    int k = idx >> 8, n = idx & 255;
    if (k >= K) return;
    float f = W[(size_t)k * 256 + n];
    unsigned u = __builtin_bit_cast(unsigned, f);
    unsigned t = u + 0x7FFF + ((u >> 16) & 1);
    float hf = __builtin_bit_cast(float, t & 0xFFFF0000u);
    unsigned short lb = f2bf_hi(f - hf);
    BThi[(size_t)n * K + k] = (unsigned short)(t >> 16);
    BTlo[(size_t)n * K + k] = lb;
}

// ---------------- CSR build
__global__ __launch_bounds__(256) void k_degree(const int* __restrict__ dst,
                                                int* __restrict__ counts, int E) {
    int e = blockIdx.x * 256 + threadIdx.x;
    if (e < E) atomicAdd(&counts[dst[e]], 1);
}

__global__ __launch_bounds__(256) void k_part(const int* __restrict__ counts,
                                              int* __restrict__ psum, int N) {
    __shared__ int red[256];
    int tid = threadIdx.x;
    int i = blockIdx.x * 256 + tid;
    red[tid] = (i < N) ? counts[i] : 0;
    __syncthreads();
    for (int off = 128; off; off >>= 1) {
        if (tid < off) red[tid] += red[tid + off];
        __syncthreads();
    }
    if (tid == 0) psum[blockIdx.x] = red[0];
}

__global__ __launch_bounds__(256) void k_scan_part(int* __restrict__ psum, int nb,
                                                   int* __restrict__ total_out) {
    __shared__ int s[256];
    int tid = threadIdx.x;
    int v = (tid < nb) ? psum[tid] : 0;
    s[tid] = v;
    __syncthreads();
    for (int off = 1; off < 256; off <<= 1) {
        int t = (tid >= off) ? s[tid - off] : 0;
        __syncthreads();
        s[tid] += t;
        __syncthreads();
    }
    if (tid < nb) psum[tid] = s[tid] - v;
    if (tid == 255) *total_out = s[255];
}

__global__ __launch_bounds__(256) void k_rowptr(const int* __restrict__ counts,
                                                const int* __restrict__ psum,
                                                int* __restrict__ rowptr,
                                                int* __restrict__ cursor, int N) {
    __shared__ int s[256];
    int tid = threadIdx.x;
    int i = blockIdx.x * 256 + tid;
    int v = (i < N) ? counts[i] : 0;
    s[tid] = v;
    __syncthreads();
    for (int off = 1; off < 256; off <<= 1) {
        int t = (tid >= off) ? s[tid - off] : 0;
        __syncthreads();
        s[tid] += t;
        __syncthreads();
    }
    if (i < N) {
        int excl = psum[blockIdx.x] + s[tid] - v;
        rowptr[i] = excl;
        cursor[i] = excl;
    }
}

__global__ __launch_bounds__(256) void k_scatter(const int* __restrict__ src,
                                                 const int* __restrict__ dst,
                                                 int* __restrict__ cursor,
                                                 int* __restrict__ col, int E) {
    int e = blockIdx.x * 256 + threadIdx.x;
    if (e < E) {
        int p = atomicAdd(&cursor[dst[e]], 1);
        col[p] = src[e];
    }
}

// ---------------- single-pass softmax+gather, HALF-WAVE per node:
// 32 lanes x ushort8 (16B) = one 512B row per half-wave per load instruction;
// each wave keeps 2 nodes' chains in flight. m = LRELU(gmax+ad) bound (monotone
// LRELU + softmax shift-invariance; e-m >= ~-10, no underflow).
__global__ __launch_bounds__(256) void k_edge(const unsigned short* __restrict__ hb,
                                              const float* __restrict__ asrc,
                                              const float* __restrict__ adst,
                                              const float* __restrict__ gmaxv,
                                              const int* __restrict__ rowptr,
                                              const int* __restrict__ col,
                                              const float* __restrict__ bias,
                                              float* __restrict__ outf,
                                              unsigned short* __restrict__ outh,
                                              unsigned short* __restrict__ outl,
                                              const float* __restrict__ gw,
                                              const float* __restrict__ gb,
                                              float* __restrict__ gatep, int N) {
    int hw = threadIdx.x >> 5;       // half-wave 0..7
    int l  = threadIdx.x & 31;       // lane-in-half-wave; features l*8..l*8+7
    int node = blockIdx.x * 8 + hw;
    if (node >= N) return;
    int j = rowptr[node], end = rowptr[node + 1];
    float ad = adst[node];
    float m = LRELU(gmaxv[0] + ad);

    float a[8];
    {
        float wself = __expf(LRELU(asrc[node] + ad) - m);
        u16x8 hv = *(const u16x8*)&hb[(size_t)node * 256 + l * 8];
#pragma unroll
        for (int e = 0; e < 8; e++)
            a[e] = wself * __builtin_bit_cast(float, (unsigned)hv[e] << 16);
        // seed denom in a separate scalar
        float denom = wself;

        for (; j + 4 <= end; j += 4) {
            int s0 = col[j], s1 = col[j + 1], s2 = col[j + 2], s3 = col[j + 3];
            float w0 = __expf(LRELU(asrc[s0] + ad) - m);
            float w1 = __expf(LRELU(asrc[s1] + ad) - m);
            float w2 = __expf(LRELU(asrc[s2] + ad) - m);
            float w3 = __expf(LRELU(asrc[s3] + ad) - m);
            denom += w0 + w1 + w2 + w3;
            u16x8 h0 = *(const u16x8*)&hb[(size_t)s0 * 256 + l * 8];
            u16x8 h1 = *(const u16x8*)&hb[(size_t)s1 * 256 + l * 8];
            u16x8 h2 = *(const u16x8*)&hb[(size_t)s2 * 256 + l * 8];
            u16x8 h3 = *(const u16x8*)&hb[(size_t)s3 * 256 + l * 8];
#pragma unroll
            for (int e = 0; e < 8; e++) {
                float f0 = __builtin_bit_cast(float, (unsigned)h0[e] << 16);
                float f1 = __builtin_bit_cast(float, (unsigned)h1[e] << 16);
                float f2 = __builtin_bit_cast(float, (unsigned)h2[e] << 16);
                float f3 = __builtin_bit_cast(float, (unsigned)h3[e] << 16);
                a[e] = fmaf(w0, f0, fmaf(w1, f1, fmaf(w2, f2, fmaf(w3, f3, a[e]))));
            }
        }
        for (; j < end; j++) {
            int s = col[j];
            float wgt = __expf(LRELU(asrc[s] + ad) - m);
            denom += wgt;
            u16x8 hx = *(const u16x8*)&hb[(size_t)s * 256 + l * 8];
#pragma unroll
            for (int e = 0; e < 8; e++)
                a[e] = fmaf(wgt, __builtin_bit_cast(float, (unsigned)hx[e] << 16), a[e]);
        }
        float inv = 1.0f / (denom + 1e-16f);
#pragma unroll
        for (int e = 0; e < 8; e++) a[e] *= inv;
    }

    float o[8];
    {
        float4 bv0 = *(const float4*)&bias[l * 8];
        float4 bv1 = *(const float4*)&bias[l * 8 + 4];
        float bb[8] = {bv0.x, bv0.y, bv0.z, bv0.w, bv1.x, bv1.y, bv1.z, bv1.w};
#pragma unroll
        for (int e = 0; e < 8; e++) o[e] = fmaxf(a[e] + bb[e], 0.0f);
    }
    if (outf) {
        float4 o0 = make_float4(o[0], o[1], o[2], o[3]);
        float4 o1 = make_float4(o[4], o[5], o[6], o[7]);
        *(float4*)&outf[(size_t)node * 256 + l * 8]     = o0;
        *(float4*)&outf[(size_t)node * 256 + l * 8 + 4] = o1;
    }
    if (outh) {
        u16x8 ph, pl;
#pragma unroll
        for (int e = 0; e < 8; e++) {
            unsigned u = __builtin_bit_cast(unsigned, o[e]);
            float hf = __builtin_bit_cast(float, u & 0xFFFF0000u);
            float fl = o[e] - hf;
            unsigned u2 = __builtin_bit_cast(unsigned, fl);
            unsigned t2 = u2 + 0x7FFF + ((u2 >> 16) & 1);
            ph[e] = (unsigned short)(u >> 16);
            pl[e] = (unsigned short)(t2 >> 16);
        }
        *(u16x8*)&outh[(size_t)node * 256 + l * 8] = ph;
        *(u16x8*)&outl[(size_t)node * 256 + l * 8] = pl;
    }
    if (gatep) {
        float s = 0.f;
#pragma unroll
        for (int e = 0; e < 8; e++) s = fmaf(o[e], gw[l * 8 + e], s);
#pragma unroll
        for (int off = 16; off; off >>= 1) s += __shfl_xor(s, off);  // width-32: stays in half-wave
        if (l == 0) gatep[node] = s + gb[0];
    }
}

// ---------------- reductions
__global__ __launch_bounds__(256) void k_pmax(const float* __restrict__ v, int N,
                                              float* __restrict__ pmax) {
    __shared__ float red[256];
    int tid = threadIdx.x;
    float m = -3.0e38f;
    for (int i = blockIdx.x * 256 + tid; i < N; i += gridDim.x * 256) m = fmaxf(m, v[i]);
    red[tid] = m;
    __syncthreads();
    for (int off = 128; off; off >>= 1) {
        if (tid < off) red[tid] = fmaxf(red[tid], red[tid + off]);
        __syncthreads();
    }
    if (tid == 0) pmax[blockIdx.x] = red[0];
}

__global__ __launch_bounds__(64) void k_fold(const float* __restrict__ p,
                                             float* __restrict__ o) {
    int lane = threadIdx.x;
    float m = p[lane];
#pragma unroll
    for (int off = 32; off; off >>= 1) m = fmaxf(m, __shfl_xor(m, off));
    if (lane == 0) o[0] = m;
}

__global__ __launch_bounds__(256) void k_gmid(const float* __restrict__ pmax, int nb,
                                              float* __restrict__ scal,
                                              float* __restrict__ gout) {
    __shared__ float red[256];
    int tid = threadIdx.x;
    red[tid] = (tid < nb) ? pmax[tid] : -3.0e38f;
    __syncthreads();
    for (int off = 128; off; off >>= 1) {
        if (tid < off) red[tid] = fmaxf(red[tid], red[tid + off]);
        __syncthreads();
    }
    if (tid == 0) { scal[0] = red[0]; scal[1] = 0.0f; }
    gout[tid] = 0.0f;
}

__global__ __launch_bounds__(256) void k_gout(const float* __restrict__ h,
                                              const float* __restrict__ gate,
                                              float* __restrict__ scal_rw,
                                              float* __restrict__ gout, int N) {
    int f = threadIdx.x;
    float gmax = scal_rw[0];
    float acc = 0.0f, sumw = 0.0f;
    for (int i = blockIdx.x; i < N; i += gridDim.x) {
        float w = __expf(gate[i] - gmax);
        acc = fmaf(w, h[(size_t)i * 256 + f], acc);
        sumw += w;
    }
    atomicAdd(&gout[f], acc);
    if (f == 0) atomicAdd(&scal_rw[1], sumw);
}

__global__ __launch_bounds__(256) void k_final(const float* __restrict__ gout,
                                               const float* __restrict__ scal,
                                               float* __restrict__ out) {
    int f = threadIdx.x;
    out[f] = gout[f] / scal[1];
}

extern "C" void kernel_launch(void* const* d_in, const int* in_sizes, int n_in,
                              void* d_out, int out_size, void* d_ws, size_t ws_size,
                              hipStream_t stream) {
    const float* x   = (const float*)d_in[0];
    const int*   ei  = (const int*)d_in[1];
    const float* W1  = (const float*)d_in[2];
    const float* b1  = (const float*)d_in[3];
    const float* as1 = (const float*)d_in[4];
    const float* ad1 = (const float*)d_in[5];
    const float* W2  = (const float*)d_in[6];
    const float* b2  = (const float*)d_in[7];
    const float* as2 = (const float*)d_in[8];
    const float* ad2 = (const float*)d_in[9];
    const float* gw  = (const float*)d_in[10];
    const float* gb  = (const float*)d_in[11];
    float* out = (float*)d_out;

    const int N = in_sizes[0] / 768;   // 50000
    const int E = in_sizes[1] / 2;     // 800000
    const int Mpad = (N + 127) & ~127; // 50048
    const int* srcA = ei;
    const int* dstA = ei + E;

    char* w = (char*)d_ws;
    auto alloc = [&](size_t bytes) -> void* {
        void* p = (void*)w;
        w += (bytes + 255) & ~(size_t)255;
        return p;
    };
    unsigned short* bufHb = (unsigned short*)alloc((size_t)N * 256 * 2);
    unsigned short* X2h = (unsigned short*)alloc((size_t)Mpad * 256 * 2);
    unsigned short* X2l = (unsigned short*)alloc((size_t)Mpad * 256 * 2);
    float* bufX = (float*)X2h;  // alias: X2 planes dead after GEMM2
    float* asrc   = (float*)alloc((size_t)N * 4);
    float* adst   = (float*)alloc((size_t)N * 4);
    float* gate   = (float*)alloc((size_t)N * 4);
    int*   counts = (int*)alloc((size_t)N * 4);
    int*   rowptr = (int*)alloc((size_t)(N + 1) * 4);
    int*   cursor = (int*)alloc((size_t)N * 4);
    int*   colbuf = (int*)alloc((size_t)E * 4);
    int*   psum   = (int*)alloc(256 * 4);
    float* pmax   = (float*)alloc(256 * 4);
    float* gmaxv  = (float*)alloc(4 * 4);
    float* scal   = (float*)alloc(8 * 4);
    float* gout   = (float*)alloc(256 * 4);
    unsigned short* BT1h = (unsigned short*)alloc((size_t)256 * 768 * 2);
    unsigned short* BT1l = (unsigned short*)alloc((size_t)256 * 768 * 2);
    unsigned short* BT2h = (unsigned short*)alloc((size_t)256 * 256 * 2);
    unsigned short* BT2l = (unsigned short*)alloc((size_t)256 * 256 * 2);

    const int eb  = (E + 255) / 256;
    const int nb8 = (N + 7) / 8;
    const int nb  = (N + 255) / 256;
    const dim3 gg(Mpad / 128, 2);

    // weight split/transpose
    k_convB<<<768, 256, 0, stream>>>(W1, BT1h, BT1l, 768);
    k_convB<<<256, 256, 0, stream>>>(W2, BT2h, BT2l, 256);

    // CSR by dst
    (void)hipMemsetAsync(counts, 0, (size_t)N * 4, stream);
    k_degree<<<eb, 256, 0, stream>>>(dstA, counts, E);
    k_part<<<nb, 256, 0, stream>>>(counts, psum, N);
    k_scan_part<<<1, 256, 0, stream>>>(psum, nb, rowptr + N);
    k_rowptr<<<nb, 256, 0, stream>>>(counts, psum, rowptr, cursor, N);
    k_scatter<<<eb, 256, 0, stream>>>(srcA, dstA, cursor, colbuf, E);

    // layer 1
    (void)hipMemsetAsync(asrc, 0, (size_t)N * 4, stream);
    (void)hipMemsetAsync(adst, 0, (size_t)N * 4, stream);
    k_gemm_f32A<<<gg, 256, 0, stream>>>(x, BT1h, BT1l, bufHb, asrc, adst, as1, ad1, N, 768);
    k_pmax<<<64, 256, 0, stream>>>(asrc, N, pmax);
    k_fold<<<1, 64, 0, stream>>>(pmax, gmaxv);
    k_edge<<<nb8, 256, 0, stream>>>(bufHb, asrc, adst, gmaxv, rowptr, colbuf, b1,
                                    nullptr, X2h, X2l, nullptr, nullptr, nullptr, N);

    // layer 2
    (void)hipMemsetAsync(asrc, 0, (size_t)N * 4, stream);
    (void)hipMemsetAsync(adst, 0, (size_t)N * 4, stream);
    k_gemm_bf16A<<<gg, 256, 0, stream>>>(X2h, X2l, BT2h, BT2l, bufHb, asrc, adst, as2, ad2, N, 256);
    k_pmax<<<64, 256, 0, stream>>>(asrc, N, pmax);
    k_fold<<<1, 64, 0, stream>>>(pmax, gmaxv);
    k_edge<<<nb8, 256, 0, stream>>>(bufHb, asrc, adst, gmaxv, rowptr, colbuf, b2,
                                    bufX, nullptr, nullptr, gw, gb, gate, N);

    // global attention
    k_pmax<<<64, 256, 0, stream>>>(gate, N, pmax);
    k_gmid<<<1, 256, 0, stream>>>(pmax, 64, scal, gout);
    k_gout<<<256, 256, 0, stream>>>(bufX, gate, scal, gout, N);
    k_final<<<1, 256, 0, stream>>>(gout, scal, out);
}

// Round 10
// 619.998 us; speedup vs baseline: 1.0378x; 1.0242x over previous
//
#include <hip/hip_runtime.h>

#define WAVE 64
#define LRELU(x) ((x) > 0.0f ? (x) : 0.2f * (x))

typedef __attribute__((ext_vector_type(8))) short bf16x8;
typedef __attribute__((ext_vector_type(8))) unsigned short u16x8;
typedef __attribute__((ext_vector_type(4))) float f32x4;

__device__ __forceinline__ void gld16(const void* g, void* l) {
    __builtin_amdgcn_global_load_lds((const __attribute__((address_space(1))) unsigned int*)g,
                                     (__attribute__((address_space(3))) unsigned int*)l,
                                     16, 0, 0);
}

__device__ __forceinline__ unsigned short f2bf_hi(float f) {
    unsigned u = __builtin_bit_cast(unsigned, f);
    u += 0x7FFF + ((u >> 16) & 1);
    return (unsigned short)(u >> 16);
}

// truncation-hi split: hi = top16(f), lo = rne_bf16(f - hi)
__device__ __forceinline__ void split8(f32x4 a, f32x4 b, bf16x8& hi, bf16x8& lo) {
    float f[8] = {a[0], a[1], a[2], a[3], b[0], b[1], b[2], b[3]};
#pragma unroll
    for (int e = 0; e < 8; e++) {
        unsigned u = __builtin_bit_cast(unsigned, f[e]);
        float hf = __builtin_bit_cast(float, u & 0xFFFF0000u);
        float fl = f[e] - hf;
        unsigned u2 = __builtin_bit_cast(unsigned, fl);
        unsigned t2 = u2 + 0x7FFF + ((u2 >> 16) & 1);
        hi[e] = (short)(u >> 16);
        lo[e] = (short)(t2 >> 16);
    }
}

// ============ GEMM layer1: 2-term split (Ahi*B + Alo*B), B single rne-bf16 plane.
// Round-9 post-mortem: kernel is LDS-pipe-bound (12 waves x 16 b128 x 12cyc ~ 2900
// cyc/CU/iter vs 700 MFMA -> MfmaUtil 24% ceiling == measured 20%). Dropping B-lo
// cuts LDS reads 16->12 and MFMA 48->32. B-rounding error ~2e-3 (threshold 6.95e-3).
__global__ __launch_bounds__(256) void k_gemm_f32A(const float* __restrict__ A,
                                                   const unsigned short* __restrict__ Bh,
                                                   unsigned short* __restrict__ Cb,
                                                   float* __restrict__ asrc,
                                                   float* __restrict__ adst,
                                                   const float* __restrict__ att_s,
                                                   const float* __restrict__ att_d,
                                                   int M, int K) {
    __shared__ char smem[24576];
    char* SAH = smem;            // A hi: 32 frags x 256B
    char* SAL = smem + 8192;     // A lo
    char* SBH = smem + 16384;    // B: 8 chunks x 1KB

    const int tid = threadIdx.x, lane = tid & 63, w = tid >> 6;
    const int m16 = lane & 15, q = lane >> 4;
    const int row0 = blockIdx.x * 128, col0 = blockIdx.y * 128;

    f32x4 acc[4][4];
#pragma unroll
    for (int i = 0; i < 4; i++)
#pragma unroll
        for (int j = 0; j < 4; j++) acc[i][j] = (f32x4){0.f, 0.f, 0.f, 0.f};

    const int s_row = tid >> 1;
    const int s_mt  = s_row >> 4, s_m16 = s_row & 15;
    const int s_q0  = (tid & 1) * 2;
    int s_grow = row0 + s_row;
    if (s_grow > M - 1) s_grow = M - 1;
    const f32x4* aptr = (const f32x4*)&A[(size_t)s_grow * K] + (tid & 1) * 4;
    const int s_off = (s_mt * 4 + s_q0) * 256 + s_m16 * 16;

    const int b_rloc = lane >> 2;
    const int b_kb   = (lane & 3) * 16;

    f32x4 pre0 = aptr[0], pre1 = aptr[1], pre2 = aptr[2], pre3 = aptr[3];

    for (int k0 = 0; k0 < K; k0 += 32) {
#pragma unroll
        for (int s = 0; s < 2; s++) {
            int c = w * 2 + s;
            int brow = col0 + c * 16 + b_rloc;
            gld16((const char*)Bh + ((size_t)brow * K + k0) * 2 + b_kb, SBH + c * 1024);
        }
        {
            bf16x8 h0, l0, h1, l1;
            split8(pre0, pre1, h0, l0);
            split8(pre2, pre3, h1, l1);
            *(bf16x8*)(SAH + s_off)       = h0;
            *(bf16x8*)(SAL + s_off)       = l0;
            *(bf16x8*)(SAH + s_off + 256) = h1;
            *(bf16x8*)(SAL + s_off + 256) = l1;
        }
        __syncthreads();

        if (k0 + 32 < K) {
            aptr += 8;
            pre0 = aptr[0]; pre1 = aptr[1]; pre2 = aptr[2]; pre3 = aptr[3];
        }

        bf16x8 bh[4];
#pragma unroll
        for (int nt = 0; nt < 4; nt++) {
            int r = (w & 1) * 64 + nt * 16 + m16;
            bh[nt] = *(bf16x8*)(SBH + r * 64 + q * 16);
        }
#pragma unroll
        for (int mt = 0; mt < 4; mt++) {
            int frag = ((w >> 1) * 4 + mt) * 4 + q;
            bf16x8 ah = *(bf16x8*)(SAH + frag * 256 + m16 * 16);
            bf16x8 al = *(bf16x8*)(SAL + frag * 256 + m16 * 16);
#pragma unroll
            for (int nt = 0; nt < 4; nt++) {
                acc[mt][nt] = __builtin_amdgcn_mfma_f32_16x16x32_bf16(ah, bh[nt], acc[mt][nt], 0, 0, 0);
                acc[mt][nt] = __builtin_amdgcn_mfma_f32_16x16x32_bf16(al, bh[nt], acc[mt][nt], 0, 0, 0);
            }
        }
        __syncthreads();
    }

    const int rbase = row0 + (w >> 1) * 64;
    const int cbase = col0 + (w & 1) * 64;
#pragma unroll
    for (int mt = 0; mt < 4; mt++)
#pragma unroll
        for (int r = 0; r < 4; r++) {
            int row = rbase + mt * 16 + q * 4 + r;
            if (row < M) {
#pragma unroll
                for (int nt = 0; nt < 4; nt++)
                    Cb[(size_t)row * 256 + cbase + nt * 16 + m16] = f2bf_hi(acc[mt][nt][r]);
            }
        }
    float as_v[4], ad_v[4];
#pragma unroll
    for (int nt = 0; nt < 4; nt++) {
        as_v[nt] = att_s[cbase + nt * 16 + m16];
        ad_v[nt] = att_d[cbase + nt * 16 + m16];
    }
#pragma unroll
    for (int mt = 0; mt < 4; mt++)
#pragma unroll
        for (int r = 0; r < 4; r++) {
            float s = 0.f, d = 0.f;
#pragma unroll
            for (int nt = 0; nt < 4; nt++) {
                float v = acc[mt][nt][r];
                s = fmaf(v, as_v[nt], s);
                d = fmaf(v, ad_v[nt], d);
            }
#pragma unroll
            for (int off = 1; off < 16; off <<= 1) {
                s += __shfl_xor(s, off);
                d += __shfl_xor(d, off);
            }
            int row = rbase + mt * 16 + q * 4 + r;
            if (m16 == 0 && row < M) {
                atomicAdd(&asrc[row], s);
                atomicAdd(&adst[row], d);
            }
        }
}

// ============ GEMM layer2: A hi/lo planes (X2), B single rne-bf16 plane.
__global__ __launch_bounds__(256) void k_gemm_bf16A(const unsigned short* __restrict__ Ah,
                                                    const unsigned short* __restrict__ Al,
                                                    const unsigned short* __restrict__ Bh,
                                                    unsigned short* __restrict__ Cb,
                                                    float* __restrict__ asrc,
                                                    float* __restrict__ adst,
                                                    const float* __restrict__ att_s,
                                                    const float* __restrict__ att_d,
                                                    int M, int K) {
    __shared__ char smem[24576];
    char* SAH = smem;
    char* SAL = smem + 8192;
    char* SBH = smem + 16384;

    const int tid = threadIdx.x, lane = tid & 63, w = tid >> 6;
    const int m16 = lane & 15, q = lane >> 4;
    const int row0 = blockIdx.x * 128, col0 = blockIdx.y * 128;

    f32x4 acc[4][4];
#pragma unroll
    for (int i = 0; i < 4; i++)
#pragma unroll
        for (int j = 0; j < 4; j++) acc[i][j] = (f32x4){0.f, 0.f, 0.f, 0.f};

    const int rloc = lane >> 2;
    const int kb   = (lane & 3) * 16;

    for (int k0 = 0; k0 < K; k0 += 32) {
#pragma unroll
        for (int s = 0; s < 2; s++) {
            int c = w * 2 + s;
            int arow = row0 + c * 16 + rloc;
            int brow = col0 + c * 16 + rloc;
            gld16((const char*)Ah + ((size_t)arow * K + k0) * 2 + kb, SAH + c * 1024);
            gld16((const char*)Al + ((size_t)arow * K + k0) * 2 + kb, SAL + c * 1024);
            gld16((const char*)Bh + ((size_t)brow * K + k0) * 2 + kb, SBH + c * 1024);
        }
        __syncthreads();

        bf16x8 bh[4];
#pragma unroll
        for (int nt = 0; nt < 4; nt++) {
            int r = (w & 1) * 64 + nt * 16 + m16;
            bh[nt] = *(bf16x8*)(SBH + r * 64 + q * 16);
        }
#pragma unroll
        for (int mt = 0; mt < 4; mt++) {
            int r = (w >> 1) * 64 + mt * 16 + m16;
            bf16x8 ah = *(bf16x8*)(SAH + r * 64 + q * 16);
            bf16x8 al = *(bf16x8*)(SAL + r * 64 + q * 16);
#pragma unroll
            for (int nt = 0; nt < 4; nt++) {
                acc[mt][nt] = __builtin_amdgcn_mfma_f32_16x16x32_bf16(ah, bh[nt], acc[mt][nt], 0, 0, 0);
                acc[mt][nt] = __builtin_amdgcn_mfma_f32_16x16x32_bf16(al, bh[nt], acc[mt][nt], 0, 0, 0);
            }
        }
        __syncthreads();
    }

    const int rbase = row0 + (w >> 1) * 64;
    const int cbase = col0 + (w & 1) * 64;
#pragma unroll
    for (int mt = 0; mt < 4; mt++)
#pragma unroll
        for (int r = 0; r < 4; r++) {
            int row = rbase + mt * 16 + q * 4 + r;
            if (row < M) {
#pragma unroll
                for (int nt = 0; nt < 4; nt++)
                    Cb[(size_t)row * 256 + cbase + nt * 16 + m16] = f2bf_hi(acc[mt][nt][r]);
            }
        }
    float as_v[4], ad_v[4];
#pragma unroll
    for (int nt = 0; nt < 4; nt++) {
        as_v[nt] = att_s[cbase + nt * 16 + m16];
        ad_v[nt] = att_d[cbase + nt * 16 + m16];
    }
#pragma unroll
    for (int mt = 0; mt < 4; mt++)
#pragma unroll
        for (int r = 0; r < 4; r++) {
            float s = 0.f, d = 0.f;
#pragma unroll
            for (int nt = 0; nt < 4; nt++) {
                float v = acc[mt][nt][r];
                s = fmaf(v, as_v[nt], s);
                d = fmaf(v, ad_v[nt], d);
            }
#pragma unroll
            for (int off = 1; off < 16; off <<= 1) {
                s += __shfl_xor(s, off);
                d += __shfl_xor(d, off);
            }
            int row = rbase + mt * 16 + q * 4 + r;
            if (m16 == 0 && row < M) {
                atomicAdd(&asrc[row], s);
                atomicAdd(&adst[row], d);
            }
        }
}

// ---------------- W [K][256] fp32 -> BT [256][K] bf16 (transpose + rne round)
__global__ __launch_bounds__(256) void k_convB(const float* __restrict__ W,
                                               unsigned short* __restrict__ BThi, int K) {
    int idx = blockIdx.x * 256 + threadIdx.x;
    int k = idx >> 8, n = idx & 255;
    if (k >= K) return;
    BThi[(size_t)n * K + k] = f2bf_hi(W[(size_t)k * 256 + n]);
}

// ---------------- CSR build
__global__ __launch_bounds__(256) void k_degree(const int* __restrict__ dst,
                                                int* __restrict__ counts, int E) {
    int e = blockIdx.x * 256 + threadIdx.x;
    if (e < E) atomicAdd(&counts[dst[e]], 1);
}

__global__ __launch_bounds__(256) void k_part(const int* __restrict__ counts,
                                              int* __restrict__ psum, int N) {
    __shared__ int red[256];
    int tid = threadIdx.x;
    int i = blockIdx.x * 256 + tid;
    red[tid] = (i < N) ? counts[i] : 0;
    __syncthreads();
    for (int off = 128; off; off >>= 1) {
        if (tid < off) red[tid] += red[tid + off];
        __syncthreads();
    }
    if (tid == 0) psum[blockIdx.x] = red[0];
}

__global__ __launch_bounds__(256) void k_scan_part(int* __restrict__ psum, int nb,
                                                   int* __restrict__ total_out) {
    __shared__ int s[256];
    int tid = threadIdx.x;
    int v = (tid < nb) ? psum[tid] : 0;
    s[tid] = v;
    __syncthreads();
    for (int off = 1; off < 256; off <<= 1) {
        int t = (tid >= off) ? s[tid - off] : 0;
        __syncthreads();
        s[tid] += t;
        __syncthreads();
    }
    if (tid < nb) psum[tid] = s[tid] - v;
    if (tid == 255) *total_out = s[255];
}

__global__ __launch_bounds__(256) void k_rowptr(const int* __restrict__ counts,
                                                const int* __restrict__ psum,
                                                int* __restrict__ rowptr,
                                                int* __restrict__ cursor, int N) {
    __shared__ int s[256];
    int tid = threadIdx.x;
    int i = blockIdx.x * 256 + tid;
    int v = (i < N) ? counts[i] : 0;
    s[tid] = v;
    __syncthreads();
    for (int off = 1; off < 256; off <<= 1) {
        int t = (tid >= off) ? s[tid - off] : 0;
        __syncthreads();
        s[tid] += t;
        __syncthreads();
    }
    if (i < N) {
        int excl = psum[blockIdx.x] + s[tid] - v;
        rowptr[i] = excl;
        cursor[i] = excl;
    }
}

__global__ __launch_bounds__(256) void k_scatter(const int* __restrict__ src,
                                                 const int* __restrict__ dst,
                                                 int* __restrict__ cursor,
                                                 int* __restrict__ col, int E) {
    int e = blockIdx.x * 256 + threadIdx.x;
    if (e < E) {
        int p = atomicAdd(&cursor[dst[e]], 1);
        col[p] = src[e];
    }
}

// ---------------- single-pass softmax+gather, half-wave per node (round-9 verified)
__global__ __launch_bounds__(256) void k_edge(const unsigned short* __restrict__ hb,
                                              const float* __restrict__ asrc,
                                              const float* __restrict__ adst,
                                              const float* __restrict__ gmaxv,
                                              const int* __restrict__ rowptr,
                                              const int* __restrict__ col,
                                              const float* __restrict__ bias,
                                              float* __restrict__ outf,
                                              unsigned short* __restrict__ outh,
                                              unsigned short* __restrict__ outl,
                                              const float* __restrict__ gw,
                                              const float* __restrict__ gb,
                                              float* __restrict__ gatep, int N) {
    int hw = threadIdx.x >> 5;
    int l  = threadIdx.x & 31;
    int node = blockIdx.x * 8 + hw;
    if (node >= N) return;
    int j = rowptr[node], end = rowptr[node + 1];
    float ad = adst[node];
    float m = LRELU(gmaxv[0] + ad);

    float a[8];
    float wself = __expf(LRELU(asrc[node] + ad) - m);
    u16x8 hv = *(const u16x8*)&hb[(size_t)node * 256 + l * 8];
#pragma unroll
    for (int e = 0; e < 8; e++)
        a[e] = wself * __builtin_bit_cast(float, (unsigned)hv[e] << 16);
    float denom = wself;

    for (; j + 4 <= end; j += 4) {
        int s0 = col[j], s1 = col[j + 1], s2 = col[j + 2], s3 = col[j + 3];
        float w0 = __expf(LRELU(asrc[s0] + ad) - m);
        float w1 = __expf(LRELU(asrc[s1] + ad) - m);
        float w2 = __expf(LRELU(asrc[s2] + ad) - m);
        float w3 = __expf(LRELU(asrc[s3] + ad) - m);
        denom += w0 + w1 + w2 + w3;
        u16x8 h0 = *(const u16x8*)&hb[(size_t)s0 * 256 + l * 8];
        u16x8 h1 = *(const u16x8*)&hb[(size_t)s1 * 256 + l * 8];
        u16x8 h2 = *(const u16x8*)&hb[(size_t)s2 * 256 + l * 8];
        u16x8 h3 = *(const u16x8*)&hb[(size_t)s3 * 256 + l * 8];
#pragma unroll
        for (int e = 0; e < 8; e++) {
            float f0 = __builtin_bit_cast(float, (unsigned)h0[e] << 16);
            float f1 = __builtin_bit_cast(float, (unsigned)h1[e] << 16);
            float f2 = __builtin_bit_cast(float, (unsigned)h2[e] << 16);
            float f3 = __builtin_bit_cast(float, (unsigned)h3[e] << 16);
            a[e] = fmaf(w0, f0, fmaf(w1, f1, fmaf(w2, f2, fmaf(w3, f3, a[e]))));
        }
    }
    for (; j < end; j++) {
        int s = col[j];
        float wgt = __expf(LRELU(asrc[s] + ad) - m);
        denom += wgt;
        u16x8 hx = *(const u16x8*)&hb[(size_t)s * 256 + l * 8];
#pragma unroll
        for (int e = 0; e < 8; e++)
            a[e] = fmaf(wgt, __builtin_bit_cast(float, (unsigned)hx[e] << 16), a[e]);
    }
    float inv = 1.0f / (denom + 1e-16f);
#pragma unroll
    for (int e = 0; e < 8; e++) a[e] *= inv;

    float o[8];
    {
        float4 bv0 = *(const float4*)&bias[l * 8];
        float4 bv1 = *(const float4*)&bias[l * 8 + 4];
        float bb[8] = {bv0.x, bv0.y, bv0.z, bv0.w, bv1.x, bv1.y, bv1.z, bv1.w};
#pragma unroll
        for (int e = 0; e < 8; e++) o[e] = fmaxf(a[e] + bb[e], 0.0f);
    }
    if (outf) {
        float4 o0 = make_float4(o[0], o[1], o[2], o[3]);
        float4 o1 = make_float4(o[4], o[5], o[6], o[7]);
        *(float4*)&outf[(size_t)node * 256 + l * 8]     = o0;
        *(float4*)&outf[(size_t)node * 256 + l * 8 + 4] = o1;
    }
    if (outh) {
        u16x8 ph, pl;
#pragma unroll
        for (int e = 0; e < 8; e++) {
            unsigned u = __builtin_bit_cast(unsigned, o[e]);
            float hf = __builtin_bit_cast(float, u & 0xFFFF0000u);
            float fl = o[e] - hf;
            unsigned u2 = __builtin_bit_cast(unsigned, fl);
            unsigned t2 = u2 + 0x7FFF + ((u2 >> 16) & 1);
            ph[e] = (unsigned short)(u >> 16);
            pl[e] = (unsigned short)(t2 >> 16);
        }
        *(u16x8*)&outh[(size_t)node * 256 + l * 8] = ph;
        *(u16x8*)&outl[(size_t)node * 256 + l * 8] = pl;
    }
    if (gatep) {
        float s = 0.f;
#pragma unroll
        for (int e = 0; e < 8; e++) s = fmaf(o[e], gw[l * 8 + e], s);
#pragma unroll
        for (int off = 16; off; off >>= 1) s += __shfl_xor(s, off);
        if (l == 0) gatep[node] = s + gb[0];
    }
}

// ---------------- reductions
__global__ __launch_bounds__(256) void k_pmax(const float* __restrict__ v, int N,
                                              float* __restrict__ pmax) {
    __shared__ float red[256];
    int tid = threadIdx.x;
    float m = -3.0e38f;
    for (int i = blockIdx.x * 256 + tid; i < N; i += gridDim.x * 256) m = fmaxf(m, v[i]);
    red[tid] = m;
    __syncthreads();
    for (int off = 128; off; off >>= 1) {
        if (tid < off) red[tid] = fmaxf(red[tid], red[tid + off]);
        __syncthreads();
    }
    if (tid == 0) pmax[blockIdx.x] = red[0];
}

__global__ __launch_bounds__(64) void k_fold(const float* __restrict__ p,
                                             float* __restrict__ o) {
    int lane = threadIdx.x;
    float m = p[lane];
#pragma unroll
    for (int off = 32; off; off >>= 1) m = fmaxf(m, __shfl_xor(m, off));
    if (lane == 0) o[0] = m;
}

__global__ __launch_bounds__(256) void k_gmid(const float* __restrict__ pmax, int nb,
                                              float* __restrict__ scal,
                                              float* __restrict__ gout) {
    __shared__ float red[256];
    int tid = threadIdx.x;
    red[tid] = (tid < nb) ? pmax[tid] : -3.0e38f;
    __syncthreads();
    for (int off = 128; off; off >>= 1) {
        if (tid < off) red[tid] = fmaxf(red[tid], red[tid + off]);
        __syncthreads();
    }
    if (tid == 0) { scal[0] = red[0]; scal[1] = 0.0f; }
    gout[tid] = 0.0f;
}

__global__ __launch_bounds__(256) void k_gout(const float* __restrict__ h,
                                              const float* __restrict__ gate,
                                              float* __restrict__ scal_rw,
                                              float* __restrict__ gout, int N) {
    int f = threadIdx.x;
    float gmax = scal_rw[0];
    float acc = 0.0f, sumw = 0.0f;
    for (int i = blockIdx.x; i < N; i += gridDim.x) {
        float w = __expf(gate[i] - gmax);
        acc = fmaf(w, h[(size_t)i * 256 + f], acc);
        sumw += w;
    }
    atomicAdd(&gout[f], acc);
    if (f == 0) atomicAdd(&scal_rw[1], sumw);
}

__global__ __launch_bounds__(256) void k_final(const float* __restrict__ gout,
                                               const float* __restrict__ scal,
                                               float* __restrict__ out) {
    int f = threadIdx.x;
    out[f] = gout[f] / scal[1];
}

extern "C" void kernel_launch(void* const* d_in, const int* in_sizes, int n_in,
                              void* d_out, int out_size, void* d_ws, size_t ws_size,
                              hipStream_t stream) {
    const float* x   = (const float*)d_in[0];
    const int*   ei  = (const int*)d_in[1];
    const float* W1  = (const float*)d_in[2];
    const float* b1  = (const float*)d_in[3];
    const float* as1 = (const float*)d_in[4];
    const float* ad1 = (const float*)d_in[5];
    const float* W2  = (const float*)d_in[6];
    const float* b2  = (const float*)d_in[7];
    const float* as2 = (const float*)d_in[8];
    const float* ad2 = (const float*)d_in[9];
    const float* gw  = (const float*)d_in[10];
    const float* gb  = (const float*)d_in[11];
    float* out = (float*)d_out;

    const int N = in_sizes[0] / 768;   // 50000
    const int E = in_sizes[1] / 2;     // 800000
    const int Mpad = (N + 127) & ~127; // 50048
    const int* srcA = ei;
    const int* dstA = ei + E;

    char* w = (char*)d_ws;
    auto alloc = [&](size_t bytes) -> void* {
        void* p = (void*)w;
        w += (bytes + 255) & ~(size_t)255;
        return p;
    };
    unsigned short* bufHb = (unsigned short*)alloc((size_t)N * 256 * 2);
    unsigned short* X2h = (unsigned short*)alloc((size_t)Mpad * 256 * 2);
    unsigned short* X2l = (unsigned short*)alloc((size_t)Mpad * 256 * 2);
    float* bufX = (float*)X2h;  // alias: X2 planes dead after GEMM2
    float* asrc   = (float*)alloc((size_t)N * 4);
    float* adst   = (float*)alloc((size_t)N * 4);
    float* gate   = (float*)alloc((size_t)N * 4);
    int*   counts = (int*)alloc((size_t)N * 4);
    int*   rowptr = (int*)alloc((size_t)(N + 1) * 4);
    int*   cursor = (int*)alloc((size_t)N * 4);
    int*   colbuf = (int*)alloc((size_t)E * 4);
    int*   psum   = (int*)alloc(256 * 4);
    float* pmax   = (float*)alloc(256 * 4);
    float* gmaxv  = (float*)alloc(4 * 4);
    float* scal   = (float*)alloc(8 * 4);
    float* gout   = (float*)alloc(256 * 4);
    unsigned short* BT1 = (unsigned short*)alloc((size_t)256 * 768 * 2);
    unsigned short* BT2 = (unsigned short*)alloc((size_t)256 * 256 * 2);

    const int eb  = (E + 255) / 256;
    const int nb8 = (N + 7) / 8;
    const int nb  = (N + 255) / 256;
    const dim3 gg(Mpad / 128, 2);

    // weight transpose + rne-bf16 (single plane)
    k_convB<<<768, 256, 0, stream>>>(W1, BT1, 768);
    k_convB<<<256, 256, 0, stream>>>(W2, BT2, 256);

    // CSR by dst
    (void)hipMemsetAsync(counts, 0, (size_t)N * 4, stream);
    k_degree<<<eb, 256, 0, stream>>>(dstA, counts, E);
    k_part<<<nb, 256, 0, stream>>>(counts, psum, N);
    k_scan_part<<<1, 256, 0, stream>>>(psum, nb, rowptr + N);
    k_rowptr<<<nb, 256, 0, stream>>>(counts, psum, rowptr, cursor, N);
    k_scatter<<<eb, 256, 0, stream>>>(srcA, dstA, cursor, colbuf, E);

    // layer 1
    (void)hipMemsetAsync(asrc, 0, (size_t)N * 4, stream);
    (void)hipMemsetAsync(adst, 0, (size_t)N * 4, stream);
    k_gemm_f32A<<<gg, 256, 0, stream>>>(x, BT1, bufHb, asrc, adst, as1, ad1, N, 768);
    k_pmax<<<64, 256, 0, stream>>>(asrc, N, pmax);
    k_fold<<<1, 64, 0, stream>>>(pmax, gmaxv);
    k_edge<<<nb8, 256, 0, stream>>>(bufHb, asrc, adst, gmaxv, rowptr, colbuf, b1,
                                    nullptr, X2h, X2l, nullptr, nullptr, nullptr, N);

    // layer 2
    (void)hipMemsetAsync(asrc, 0, (size_t)N * 4, stream);
    (void)hipMemsetAsync(adst, 0, (size_t)N * 4, stream);
    k_gemm_bf16A<<<gg, 256, 0, stream>>>(X2h, X2l, BT2, bufHb, asrc, adst, as2, ad2, N, 256);
    k_pmax<<<64, 256, 0, stream>>>(asrc, N, pmax);
    k_fold<<<1, 64, 0, stream>>>(pmax, gmaxv);
    k_edge<<<nb8, 256, 0, stream>>>(bufHb, asrc, adst, gmaxv, rowptr, colbuf, b2,
                                    bufX, nullptr, nullptr, gw, gb, gate, N);

    // global attention
    k_pmax<<<64, 256, 0, stream>>>(gate, N, pmax);
    k_gmid<<<1, 256, 0, stream>>>(pmax, 64, scal, gout);
    k_gout<<<256, 256, 0, stream>>>(bufX, gate, scal, gout, N);
    k_final<<<1, 256, 0, stream>>>(gout, scal, out);
}